// Round 1
// baseline (2603.505 us; speedup 1.0000x reference)
//
#include <hip/hip_runtime.h>
#include <math.h>

#define BB 4
#define NN 2048
#define KNN 20

// ---------------------------------------------------------------------------
// KNN: one block per (b, i). Exact IEEE (no-FMA) distance to match numpy ref
// ordering; stable argmin x20 with lower-index tie-break == lax.top_k(-d2).
// ---------------------------------------------------------------------------
__global__ __launch_bounds__(256) void knn_kernel(const float* __restrict__ pc,
                                                  int* __restrict__ idx_out,
                                                  float* __restrict__ rel_out) {
    __shared__ float sx[NN], sy[NN], sz[NN], d2s[NN];
    __shared__ float rv[256];
    __shared__ int ri[256];
    const int tid = threadIdx.x;
    const int b = blockIdx.x / NN;
    const int i = blockIdx.x % NN;
    for (int j = tid; j < NN; j += 256) {
        sx[j] = pc[(size_t)(b * NN + j) * 6 + 0];
        sy[j] = pc[(size_t)(b * NN + j) * 6 + 1];
        sz[j] = pc[(size_t)(b * NN + j) * 6 + 2];
    }
    __syncthreads();
    const float xi = sx[i], yi = sy[i], zi = sz[i];
    const float sqi = __fadd_rn(__fadd_rn(__fmul_rn(xi, xi), __fmul_rn(yi, yi)), __fmul_rn(zi, zi));
    for (int j = tid; j < NN; j += 256) {
        float xj = sx[j], yj = sy[j], zj = sz[j];
        float sqj = __fadd_rn(__fadd_rn(__fmul_rn(xj, xj), __fmul_rn(yj, yj)), __fmul_rn(zj, zj));
        float dot = __fadd_rn(__fadd_rn(__fmul_rn(xi, xj), __fmul_rn(yi, yj)), __fmul_rn(zi, zj));
        d2s[j] = __fsub_rn(__fadd_rn(sqi, sqj), __fmul_rn(2.0f, dot));
    }
    __syncthreads();
    for (int k = 0; k < KNN; ++k) {
        float bv = INFINITY;
        int bi = NN;
        for (int j = tid; j < NN; j += 256) {
            float v = d2s[j];
            if (v < bv || (v == bv && j < bi)) { bv = v; bi = j; }
        }
        rv[tid] = bv; ri[tid] = bi;
        __syncthreads();
        for (int s = 128; s > 0; s >>= 1) {
            if (tid < s) {
                float v2 = rv[tid + s]; int i2 = ri[tid + s];
                if (v2 < rv[tid] || (v2 == rv[tid] && i2 < ri[tid])) { rv[tid] = v2; ri[tid] = i2; }
            }
            __syncthreads();
        }
        const int w = ri[0];
        if (tid == 0) {
            d2s[w] = INFINITY;
            idx_out[((size_t)(b * NN + i)) * KNN + k] = w;
            size_t ro = (((size_t)(b * NN + i)) * KNN + k) * 3;
            rel_out[ro + 0] = sx[w] - xi;
            rel_out[ro + 1] = sy[w] - yi;
            rel_out[ro + 2] = sz[w] - zi;
        }
        __syncthreads();
    }
}

// ---------------------------------------------------------------------------
// Per-layer taylor: t[o] = b1[o] + sum_t w1[o,t]*terms[t],  layout (B,N,K,3)
// ---------------------------------------------------------------------------
__global__ __launch_bounds__(256) void taylor_kernel(const float* __restrict__ rel,
                                                     const float* __restrict__ w1,
                                                     const float* __restrict__ b1,
                                                     float* __restrict__ ty) {
    int t = blockIdx.x * 256 + threadIdx.x;
    if (t >= BB * NN * KNN) return;
    float X = rel[(size_t)t * 3 + 0], Y = rel[(size_t)t * 3 + 1], Z = rel[(size_t)t * 3 + 2];
    float tm[20];
    tm[0] = 1.f; tm[1] = X; tm[2] = Y; tm[3] = Z;
    tm[4] = X * Y; tm[5] = X * Z; tm[6] = Y * Z;
    tm[7] = X * X; tm[8] = Y * Y; tm[9] = Z * Z;
    tm[10] = X * X * Y; tm[11] = X * X * Z; tm[12] = X * Y * Y; tm[13] = Y * Y * Z;
    tm[14] = X * Z * Z; tm[15] = Y * Z * Z; tm[16] = X * Y * Z;
    tm[17] = X * X * X; tm[18] = Y * Y * Y; tm[19] = Z * Z * Z;
#pragma unroll
    for (int o = 0; o < 3; ++o) {
        float a = b1[o];
#pragma unroll
        for (int q = 0; q < 20; ++q) a += w1[o * 20 + q] * tm[q];
        ty[(size_t)t * 3 + o] = a;
    }
}

// w2 (COUT, CK3, 20) -> w2t (20, CK3, COUT)
__global__ __launch_bounds__(256) void w2t_kernel(const float* __restrict__ w2,
                                                  float* __restrict__ w2t,
                                                  int COUT, int CK3) {
    int e = blockIdx.x * 256 + threadIdx.x;
    int total = COUT * CK3 * KNN;
    if (e >= total) return;
    int oc = e / (CK3 * KNN);
    int r = e % (CK3 * KNN);
    int ck = r / KNN;
    int kk = r % KNN;
    w2t[((size_t)kk * CK3 + ck) * COUT + oc] = w2[e];
}

// ---------------------------------------------------------------------------
// SpiderConv as tiled GEMM. fin layout (B,N,CIN), fout (B,N,COUT).
// out[oc,n] = relu(b2[oc] + sum_{k,c,o} fin[idx[n,k],c] * ty[n,k,o] * w2t[k, c*3+o, oc])
// ---------------------------------------------------------------------------
template <int CIN, int COUT, int OT, int NT, int CC>
__global__ __launch_bounds__(256) void conv_kernel(const float* __restrict__ fin,
                                                   const int* __restrict__ idx,
                                                   const float* __restrict__ ty,
                                                   const float* __restrict__ w2t,
                                                   const float* __restrict__ b2,
                                                   float* __restrict__ fout) {
    constexpr int R = CC * 3;
    constexpr int CK3 = CIN * 3;
    constexpr int NTILES = NN / NT;
    constexpr int OCTILES = COUT / OT;
    __shared__ __align__(16) float Asm[R * OT];
    __shared__ __align__(16) float Bsm[R * NT];
    __shared__ int jn[NT];
    __shared__ float tl[NT * 3];
    const int tid = threadIdx.x;
    const int blk = blockIdx.x;
    const int b = blk / (NTILES * OCTILES);
    const int rem = blk % (NTILES * OCTILES);
    const int n0 = (rem / OCTILES) * NT;
    const int oc0 = (rem % OCTILES) * OT;

    float acc[4][4] = {};
    const int tx = tid % (NT / 4);
    const int tyi = tid / (NT / 4);

    for (int k = 0; k < KNN; ++k) {
        for (int c0 = 0; c0 < CIN; c0 += CC) {
            __syncthreads();
            if (tid < NT) {
                int j = idx[((size_t)(b * NN) + n0 + tid) * KNN + k];
                jn[tid] = j;
                size_t to = (((size_t)(b * NN) + n0 + tid) * KNN + k) * 3;
                tl[tid * 3 + 0] = ty[to + 0];
                tl[tid * 3 + 1] = ty[to + 1];
                tl[tid * 3 + 2] = ty[to + 2];
            }
            __syncthreads();
            for (int e = tid; e < R * OT; e += 256) {
                int r = e / OT, oc = e % OT;
                Asm[e] = w2t[((size_t)k * CK3 + c0 * 3 + r) * COUT + oc0 + oc];
            }
            for (int e = tid; e < R * NT; e += 256) {
                int r = e / NT, n = e % NT;
                float g = fin[((size_t)(b * NN) + jn[n]) * CIN + c0 + r / 3];
                Bsm[e] = g * tl[n * 3 + r % 3];
            }
            __syncthreads();
#pragma unroll 6
            for (int r = 0; r < R; ++r) {
                const float4 a4 = *reinterpret_cast<const float4*>(&Asm[r * OT + tyi * 4]);
                const float4 b4 = *reinterpret_cast<const float4*>(&Bsm[r * NT + tx * 4]);
                const float av[4] = {a4.x, a4.y, a4.z, a4.w};
                const float bv[4] = {b4.x, b4.y, b4.z, b4.w};
#pragma unroll
                for (int i2 = 0; i2 < 4; ++i2)
#pragma unroll
                    for (int j2 = 0; j2 < 4; ++j2) acc[i2][j2] += av[i2] * bv[j2];
            }
        }
    }
    float bias[4];
#pragma unroll
    for (int i2 = 0; i2 < 4; ++i2) bias[i2] = b2[oc0 + tyi * 4 + i2];
#pragma unroll
    for (int j2 = 0; j2 < 4; ++j2) {
        int n = n0 + tx * 4 + j2;
        float4 o4;
        o4.x = fmaxf(acc[0][j2] + bias[0], 0.f);
        o4.y = fmaxf(acc[1][j2] + bias[1], 0.f);
        o4.z = fmaxf(acc[2][j2] + bias[2], 0.f);
        o4.w = fmaxf(acc[3][j2] + bias[3], 0.f);
        *reinterpret_cast<float4*>(&fout[((size_t)(b * NN) + n) * COUT + oc0 + tyi * 4]) = o4;
    }
}

// ---------------------------------------------------------------------------
// top-2 over N per (b, channel); cat order f1|f2|f3|f4 -> out (B, 480*2)
// ---------------------------------------------------------------------------
__global__ __launch_bounds__(256) void top2_kernel(const float* __restrict__ f1,
                                                   const float* __restrict__ f2,
                                                   const float* __restrict__ f3,
                                                   const float* __restrict__ f4,
                                                   float* __restrict__ out) {
    __shared__ float m1s[256], m2s[256];
    const int bid = blockIdx.x;
    const int b = bid / 480;
    const int ch = bid % 480;
    const float* f; int C, c;
    if (ch < 32)       { f = f1; C = 32;  c = ch; }
    else if (ch < 96)  { f = f2; C = 64;  c = ch - 32; }
    else if (ch < 224) { f = f3; C = 128; c = ch - 96; }
    else               { f = f4; C = 256; c = ch - 224; }
    float m1 = -INFINITY, m2 = -INFINITY;
    for (int n = threadIdx.x; n < NN; n += 256) {
        float v = f[((size_t)(b * NN) + n) * C + c];
        if (v > m1) { m2 = m1; m1 = v; }
        else if (v > m2) m2 = v;
    }
    m1s[threadIdx.x] = m1; m2s[threadIdx.x] = m2;
    __syncthreads();
    for (int s = 128; s > 0; s >>= 1) {
        if (threadIdx.x < s) {
            float a1 = m1s[threadIdx.x], a2 = m2s[threadIdx.x];
            float c1 = m1s[threadIdx.x + s], c2 = m2s[threadIdx.x + s];
            m1s[threadIdx.x] = fmaxf(a1, c1);
            m2s[threadIdx.x] = fmaxf(fminf(a1, c1), fmaxf(a2, c2));
        }
        __syncthreads();
    }
    if (threadIdx.x == 0) {
        out[(size_t)b * 960 + ch * 2 + 0] = m1s[0];
        out[(size_t)b * 960 + ch * 2 + 1] = m2s[0];
    }
}

extern "C" void kernel_launch(void* const* d_in, const int* in_sizes, int n_in,
                              void* d_out, int out_size, void* d_ws, size_t ws_size,
                              hipStream_t stream) {
    const float* pc = (const float*)d_in[0];
    const float *w1[4], *b1[4], *w2[4], *b2[4];
    for (int l = 0; l < 4; ++l) {
        w1[l] = (const float*)d_in[1 + 4 * l];
        b1[l] = (const float*)d_in[2 + 4 * l];
        w2[l] = (const float*)d_in[3 + 4 * l];
        b2[l] = (const float*)d_in[4 + 4 * l];
    }
    char* ws = (char*)d_ws;
    size_t off = 0;
    auto alloc = [&](size_t bytes) -> void* {
        void* p = ws + off;
        off = (off + bytes + 255) & ~(size_t)255;
        return p;
    };
    int* idxb  = (int*)alloc((size_t)BB * NN * KNN * 4);
    float* rel = (float*)alloc((size_t)BB * NN * KNN * 3 * 4);
    float* tyb = (float*)alloc((size_t)BB * NN * KNN * 3 * 4);
    float* w2t = (float*)alloc((size_t)256 * 384 * 20 * 4);
    float* f1  = (float*)alloc((size_t)BB * NN * 32 * 4);
    float* f2  = (float*)alloc((size_t)BB * NN * 64 * 4);
    float* f3  = (float*)alloc((size_t)BB * NN * 128 * 4);
    float* f4  = (float*)alloc((size_t)BB * NN * 256 * 4);

    knn_kernel<<<BB * NN, 256, 0, stream>>>(pc, idxb, rel);

    const int tgrid = (BB * NN * KNN + 255) / 256;

    // layer 0: cin=6, cout=32
    taylor_kernel<<<tgrid, 256, 0, stream>>>(rel, w1[0], b1[0], tyb);
    w2t_kernel<<<(32 * 18 * 20 + 255) / 256, 256, 0, stream>>>(w2[0], w2t, 32, 18);
    conv_kernel<6, 32, 32, 128, 6><<<BB * (NN / 128) * 1, 256, 0, stream>>>(pc, idxb, tyb, w2t, b2[0], f1);

    // layer 1: cin=32, cout=64
    taylor_kernel<<<tgrid, 256, 0, stream>>>(rel, w1[1], b1[1], tyb);
    w2t_kernel<<<(64 * 96 * 20 + 255) / 256, 256, 0, stream>>>(w2[1], w2t, 64, 96);
    conv_kernel<32, 64, 64, 64, 16><<<BB * (NN / 64) * 1, 256, 0, stream>>>(f1, idxb, tyb, w2t, b2[1], f2);

    // layer 2: cin=64, cout=128
    taylor_kernel<<<tgrid, 256, 0, stream>>>(rel, w1[2], b1[2], tyb);
    w2t_kernel<<<(128 * 192 * 20 + 255) / 256, 256, 0, stream>>>(w2[2], w2t, 128, 192);
    conv_kernel<64, 128, 64, 64, 16><<<BB * (NN / 64) * 2, 256, 0, stream>>>(f2, idxb, tyb, w2t, b2[2], f3);

    // layer 3: cin=128, cout=256
    taylor_kernel<<<tgrid, 256, 0, stream>>>(rel, w1[3], b1[3], tyb);
    w2t_kernel<<<(256 * 384 * 20 + 255) / 256, 256, 0, stream>>>(w2[3], w2t, 256, 384);
    conv_kernel<128, 256, 64, 64, 16><<<BB * (NN / 64) * 4, 256, 0, stream>>>(f3, idxb, tyb, w2t, b2[3], f4);

    top2_kernel<<<BB * 480, 256, 0, stream>>>(f1, f2, f3, f4, (float*)d_out);
}

// Round 2
// 1066.023 us; speedup vs baseline: 2.4423x; 2.4423x over previous
//
#include <hip/hip_runtime.h>
#include <math.h>

#define BB 4
#define NN 2048
#define KNN 20

// ---------------------------------------------------------------------------
// KNN: one WAVE per point. d2 in registers; selection via lexicographic
// (value, index) running threshold -> exact lax.top_k(-d2) order, no barriers.
// IEEE no-FMA arithmetic identical to numpy reference.
// ---------------------------------------------------------------------------
__global__ __launch_bounds__(256) void knn_kernel(const float* __restrict__ pc,
                                                  int* __restrict__ idx_out,
                                                  float* __restrict__ rel_out) {
    __shared__ float sx[NN], sy[NN], sz[NN];
    const int tid = threadIdx.x;
    const int b = blockIdx.x / (NN / 4);
    const int grp = blockIdx.x % (NN / 4);
    for (int p = tid; p < NN; p += 256) {
        sx[p] = pc[(size_t)(b * NN + p) * 6 + 0];
        sy[p] = pc[(size_t)(b * NN + p) * 6 + 1];
        sz[p] = pc[(size_t)(b * NN + p) * 6 + 2];
    }
    __syncthreads();
    const int lane = tid & 63;
    const int wv = tid >> 6;
    const int i = grp * 4 + wv;
    const float xi = sx[i], yi = sy[i], zi = sz[i];
    const float sqi = __fadd_rn(__fadd_rn(__fmul_rn(xi, xi), __fmul_rn(yi, yi)), __fmul_rn(zi, zi));
    float d2r[32];
#pragma unroll
    for (int t = 0; t < 32; ++t) {
        int j = t * 64 + lane;
        float xj = sx[j], yj = sy[j], zj = sz[j];
        float sqj = __fadd_rn(__fadd_rn(__fmul_rn(xj, xj), __fmul_rn(yj, yj)), __fmul_rn(zj, zj));
        float dot = __fadd_rn(__fadd_rn(__fmul_rn(xi, xj), __fmul_rn(yi, yj)), __fmul_rn(zi, zj));
        d2r[t] = __fsub_rn(__fadd_rn(sqi, sqj), __fmul_rn(2.0f, dot));
    }
    float lv = -INFINITY; int lj = -1;
    for (int k = 0; k < KNN; ++k) {
        float bv = INFINITY; int bj = 0x7fffffff;
#pragma unroll
        for (int t = 0; t < 32; ++t) {
            int j = t * 64 + lane;
            float v = d2r[t];
            bool gt = (v > lv) || (v == lv && j > lj);
            bool lt = (v < bv) || (v == bv && j < bj);
            if (gt && lt) { bv = v; bj = j; }
        }
#pragma unroll
        for (int m = 32; m >= 1; m >>= 1) {
            float ov = __shfl_xor(bv, m, 64);
            int oj = __shfl_xor(bj, m, 64);
            if (ov < bv || (ov == bv && oj < bj)) { bv = ov; bj = oj; }
        }
        lv = bv; lj = bj;
        if (lane == 0) {
            idx_out[((size_t)(b * NN + i)) * KNN + k] = bj;
            size_t ro = (((size_t)(b * NN + i)) * KNN + k) * 3;
            rel_out[ro + 0] = __fsub_rn(sx[bj], xi);
            rel_out[ro + 1] = __fsub_rn(sy[bj], yi);
            rel_out[ro + 2] = __fsub_rn(sz[bj], zi);
        }
    }
}

// ---------------------------------------------------------------------------
// Per-layer taylor: t[o] = b1[o] + sum_t w1[o,t]*terms[t],  layout (B,N,K,3)
// ---------------------------------------------------------------------------
__global__ __launch_bounds__(256) void taylor_kernel(const float* __restrict__ rel,
                                                     const float* __restrict__ w1,
                                                     const float* __restrict__ b1,
                                                     float* __restrict__ ty) {
    int t = blockIdx.x * 256 + threadIdx.x;
    if (t >= BB * NN * KNN) return;
    float X = rel[(size_t)t * 3 + 0], Y = rel[(size_t)t * 3 + 1], Z = rel[(size_t)t * 3 + 2];
    float tm[20];
    tm[0] = 1.f; tm[1] = X; tm[2] = Y; tm[3] = Z;
    tm[4] = X * Y; tm[5] = X * Z; tm[6] = Y * Z;
    tm[7] = X * X; tm[8] = Y * Y; tm[9] = Z * Z;
    tm[10] = X * X * Y; tm[11] = X * X * Z; tm[12] = X * Y * Y; tm[13] = Y * Y * Z;
    tm[14] = X * Z * Z; tm[15] = Y * Z * Z; tm[16] = X * Y * Z;
    tm[17] = X * X * X; tm[18] = Y * Y * Y; tm[19] = Z * Z * Z;
#pragma unroll
    for (int o = 0; o < 3; ++o) {
        float a = b1[o];
#pragma unroll
        for (int q = 0; q < 20; ++q) a += w1[o * 20 + q] * tm[q];
        ty[(size_t)t * 3 + o] = a;
    }
}

// w2 (COUT, CIN*3, 20) -> w2t [k][o][c][oc]
__global__ __launch_bounds__(256) void w2t_kernel(const float* __restrict__ w2,
                                                  float* __restrict__ w2t,
                                                  int COUT, int CIN) {
    int e = blockIdx.x * 256 + threadIdx.x;
    int CK3 = CIN * 3;
    int total = COUT * CK3 * KNN;
    if (e >= total) return;
    int oc = e / (CK3 * KNN);
    int rem = e % (CK3 * KNN);
    int rr = rem / KNN;
    int kk = rem % KNN;
    int c = rr / 3;
    int o = rr % 3;
    w2t[(((size_t)kk * 3 + o) * CIN + c) * COUT + oc] = w2[e];
}

// ---------------------------------------------------------------------------
// SpiderConv GEMM. fin (B,N,CIN), fout (B,N,COUT).
// out[n,oc] = relu(b2[oc] + sum_k sum_o ty[n,k,o] * sum_c fin[idx[n,k],c]*w2t[k,o,c,oc])
// Fsm staged [c][n] (transposed, float4 channel gathers); 3 per-o accumulator
// sets; taylor factor applied once per k.
// ---------------------------------------------------------------------------
template <int CIN, int COUT, int NT, int OT, int CC, int TM, int TN>
__global__ __launch_bounds__(256) void conv_kernel(const float* __restrict__ fin,
                                                   const int* __restrict__ idx,
                                                   const float* __restrict__ ty,
                                                   const float* __restrict__ w2t,
                                                   const float* __restrict__ b2,
                                                   float* __restrict__ fout) {
    constexpr int NTILES = NN / NT;
    constexpr int OCT = COUT / OT;
    constexpr int NCH = CIN / CC;
    __shared__ __align__(16) float Fsm[CC][NT];
    __shared__ __align__(16) float Asm[3][CC][OT];
    __shared__ __align__(16) float tl[3][NT];
    const int tid = threadIdx.x;
    const int bid = blockIdx.x;
    const int oct = bid % OCT;
    const int nt = (bid / OCT) % NTILES;
    const int b = bid / (OCT * NTILES);
    const int n0 = nt * NT;
    const int oc0 = oct * OT;
    const int tx = tid % (NT / TN);
    const int tyi = tid / (NT / TN);
    const size_t inrow = (size_t)b * NN;

    float acc[TM][TN] = {};
    float acc_o[3][TM][TN] = {};

#pragma unroll 1
    for (int k = 0; k < KNN; ++k) {
#pragma unroll 1
        for (int ch = 0; ch < NCH; ++ch) {
            const int c0 = ch * CC;
            __syncthreads();
            // ---- stage Fsm[cc][n] via gather ----
            if constexpr (CC % 4 == 0) {
                constexpr int NV = CC * NT / 4;
                for (int v = tid; v < NV; v += 256) {
                    int n = v % NT;
                    int c4 = v / NT;
                    int j = idx[(inrow + n0 + n) * KNN + k];
                    const float4 g = *reinterpret_cast<const float4*>(
                        &fin[(inrow + j) * CIN + c0 + c4 * 4]);
                    Fsm[c4 * 4 + 0][n] = g.x;
                    Fsm[c4 * 4 + 1][n] = g.y;
                    Fsm[c4 * 4 + 2][n] = g.z;
                    Fsm[c4 * 4 + 3][n] = g.w;
                }
            } else {
                for (int v = tid; v < CC * NT; v += 256) {
                    int n = v % NT;
                    int cc = v / NT;
                    int j = idx[(inrow + n0 + n) * KNN + k];
                    Fsm[cc][n] = fin[(inrow + j) * CIN + c0 + cc];
                }
            }
            // ---- stage Asm ----
            constexpr int AE = 3 * CC * OT;
            for (int e = tid; e < AE; e += 256) {
                int oc = e % OT;
                int c = (e / OT) % CC;
                int o = e / (OT * CC);
                Asm[o][c][oc] = w2t[(((size_t)k * 3 + o) * CIN + c0 + c) * COUT + oc0 + oc];
            }
            // ---- stage tl (once per k) ----
            if (ch == 0) {
                for (int e = tid; e < 3 * NT; e += 256) {
                    int o = e / NT;
                    int n = e % NT;
                    tl[o][n] = ty[((inrow + n0 + n) * KNN + k) * 3 + o];
                }
            }
            __syncthreads();
            // ---- compute ----
#pragma unroll
            for (int c = 0; c < CC; ++c) {
                float Fv[TN];
                if constexpr (TN == 4) {
                    float4 f = *reinterpret_cast<const float4*>(&Fsm[c][tx * 4]);
                    Fv[0] = f.x; Fv[1] = f.y; Fv[2] = f.z; Fv[3] = f.w;
                } else {
                    float2 f = *reinterpret_cast<const float2*>(&Fsm[c][tx * 2]);
                    Fv[0] = f.x; Fv[1] = f.y;
                }
#pragma unroll
                for (int o = 0; o < 3; ++o) {
                    float Av[TM];
                    if constexpr (TM == 4) {
                        float4 a = *reinterpret_cast<const float4*>(&Asm[o][c][tyi * 4]);
                        Av[0] = a.x; Av[1] = a.y; Av[2] = a.z; Av[3] = a.w;
                    } else {
                        float2 a = *reinterpret_cast<const float2*>(&Asm[o][c][tyi * 2]);
                        Av[0] = a.x; Av[1] = a.y;
                    }
#pragma unroll
                    for (int m = 0; m < TM; ++m)
#pragma unroll
                        for (int n = 0; n < TN; ++n) acc_o[o][m][n] += Av[m] * Fv[n];
                }
            }
        }
        // ---- combine with taylor factors, reset acc_o ----
        float tlv[3][TN];
#pragma unroll
        for (int o = 0; o < 3; ++o) {
            if constexpr (TN == 4) {
                float4 f = *reinterpret_cast<const float4*>(&tl[o][tx * 4]);
                tlv[o][0] = f.x; tlv[o][1] = f.y; tlv[o][2] = f.z; tlv[o][3] = f.w;
            } else {
                float2 f = *reinterpret_cast<const float2*>(&tl[o][tx * 2]);
                tlv[o][0] = f.x; tlv[o][1] = f.y;
            }
        }
#pragma unroll
        for (int o = 0; o < 3; ++o)
#pragma unroll
            for (int m = 0; m < TM; ++m)
#pragma unroll
                for (int n = 0; n < TN; ++n) {
                    acc[m][n] += tlv[o][n] * acc_o[o][m][n];
                    acc_o[o][m][n] = 0.f;
                }
    }
    // ---- epilogue: bias + relu ----
    float bias[TM];
#pragma unroll
    for (int m = 0; m < TM; ++m) bias[m] = b2[oc0 + tyi * TM + m];
#pragma unroll
    for (int n = 0; n < TN; ++n) {
        int nn = n0 + tx * TN + n;
        float* dst = &fout[(inrow + nn) * COUT + oc0 + tyi * TM];
        if constexpr (TM == 4) {
            float4 o4;
            o4.x = fmaxf(acc[0][n] + bias[0], 0.f);
            o4.y = fmaxf(acc[1][n] + bias[1], 0.f);
            o4.z = fmaxf(acc[2][n] + bias[2], 0.f);
            o4.w = fmaxf(acc[3][n] + bias[3], 0.f);
            *reinterpret_cast<float4*>(dst) = o4;
        } else {
            float2 o2;
            o2.x = fmaxf(acc[0][n] + bias[0], 0.f);
            o2.y = fmaxf(acc[1][n] + bias[1], 0.f);
            *reinterpret_cast<float2*>(dst) = o2;
        }
    }
}

// ---------------------------------------------------------------------------
// top-2 over N per (b, channel); cat order f1|f2|f3|f4 -> out (B, 480*2)
// ---------------------------------------------------------------------------
__global__ __launch_bounds__(256) void top2_kernel(const float* __restrict__ f1,
                                                   const float* __restrict__ f2,
                                                   const float* __restrict__ f3,
                                                   const float* __restrict__ f4,
                                                   float* __restrict__ out) {
    __shared__ float m1s[256], m2s[256];
    const int bid = blockIdx.x;
    const int b = bid / 480;
    const int ch = bid % 480;
    const float* f; int C, c;
    if (ch < 32)       { f = f1; C = 32;  c = ch; }
    else if (ch < 96)  { f = f2; C = 64;  c = ch - 32; }
    else if (ch < 224) { f = f3; C = 128; c = ch - 96; }
    else               { f = f4; C = 256; c = ch - 224; }
    float m1 = -INFINITY, m2 = -INFINITY;
    for (int n = threadIdx.x; n < NN; n += 256) {
        float v = f[((size_t)(b * NN) + n) * C + c];
        if (v > m1) { m2 = m1; m1 = v; }
        else if (v > m2) m2 = v;
    }
    m1s[threadIdx.x] = m1; m2s[threadIdx.x] = m2;
    __syncthreads();
    for (int s = 128; s > 0; s >>= 1) {
        if (threadIdx.x < s) {
            float a1 = m1s[threadIdx.x], a2 = m2s[threadIdx.x];
            float c1 = m1s[threadIdx.x + s], c2 = m2s[threadIdx.x + s];
            m1s[threadIdx.x] = fmaxf(a1, c1);
            m2s[threadIdx.x] = fmaxf(fminf(a1, c1), fmaxf(a2, c2));
        }
        __syncthreads();
    }
    if (threadIdx.x == 0) {
        out[(size_t)b * 960 + ch * 2 + 0] = m1s[0];
        out[(size_t)b * 960 + ch * 2 + 1] = m2s[0];
    }
}

extern "C" void kernel_launch(void* const* d_in, const int* in_sizes, int n_in,
                              void* d_out, int out_size, void* d_ws, size_t ws_size,
                              hipStream_t stream) {
    const float* pc = (const float*)d_in[0];
    const float *w1[4], *b1[4], *w2[4], *b2[4];
    for (int l = 0; l < 4; ++l) {
        w1[l] = (const float*)d_in[1 + 4 * l];
        b1[l] = (const float*)d_in[2 + 4 * l];
        w2[l] = (const float*)d_in[3 + 4 * l];
        b2[l] = (const float*)d_in[4 + 4 * l];
    }
    char* ws = (char*)d_ws;
    size_t off = 0;
    auto alloc = [&](size_t bytes) -> void* {
        void* p = ws + off;
        off = (off + bytes + 255) & ~(size_t)255;
        return p;
    };
    int* idxb  = (int*)alloc((size_t)BB * NN * KNN * 4);
    float* rel = (float*)alloc((size_t)BB * NN * KNN * 3 * 4);
    float* tyb = (float*)alloc((size_t)BB * NN * KNN * 3 * 4);
    float* w2t = (float*)alloc((size_t)256 * 384 * 20 * 4);
    float* f1  = (float*)alloc((size_t)BB * NN * 32 * 4);
    float* f2  = (float*)alloc((size_t)BB * NN * 64 * 4);
    float* f3  = (float*)alloc((size_t)BB * NN * 128 * 4);
    float* f4  = (float*)alloc((size_t)BB * NN * 256 * 4);

    knn_kernel<<<BB * NN / 4, 256, 0, stream>>>(pc, idxb, rel);

    const int tgrid = (BB * NN * KNN + 255) / 256;

    // layer 0: cin=6, cout=32
    taylor_kernel<<<tgrid, 256, 0, stream>>>(rel, w1[0], b1[0], tyb);
    w2t_kernel<<<(32 * 18 * 20 + 255) / 256, 256, 0, stream>>>(w2[0], w2t, 32, 6);
    conv_kernel<6, 32, 32, 32, 6, 2, 2>
        <<<BB * (NN / 32) * 1, 256, 0, stream>>>(pc, idxb, tyb, w2t, b2[0], f1);

    // layer 1: cin=32, cout=64
    taylor_kernel<<<tgrid, 256, 0, stream>>>(rel, w1[1], b1[1], tyb);
    w2t_kernel<<<(64 * 96 * 20 + 255) / 256, 256, 0, stream>>>(w2[1], w2t, 64, 32);
    conv_kernel<32, 64, 32, 32, 32, 2, 2>
        <<<BB * (NN / 32) * 2, 256, 0, stream>>>(f1, idxb, tyb, w2t, b2[1], f2);

    // layer 2: cin=64, cout=128
    taylor_kernel<<<tgrid, 256, 0, stream>>>(rel, w1[2], b1[2], tyb);
    w2t_kernel<<<(128 * 192 * 20 + 255) / 256, 256, 0, stream>>>(w2[2], w2t, 128, 64);
    conv_kernel<64, 128, 64, 32, 32, 2, 4>
        <<<BB * (NN / 64) * 4, 256, 0, stream>>>(f2, idxb, tyb, w2t, b2[2], f3);

    // layer 3: cin=128, cout=256
    taylor_kernel<<<tgrid, 256, 0, stream>>>(rel, w1[3], b1[3], tyb);
    w2t_kernel<<<(256 * 384 * 20 + 255) / 256, 256, 0, stream>>>(w2[3], w2t, 256, 128);
    conv_kernel<128, 256, 64, 32, 32, 2, 4>
        <<<BB * (NN / 64) * 8, 256, 0, stream>>>(f3, idxb, tyb, w2t, b2[3], f4);

    top2_kernel<<<BB * 480, 256, 0, stream>>>(f1, f2, f3, f4, (float*)d_out);
}

// Round 3
// 591.159 us; speedup vs baseline: 4.4041x; 1.8033x over previous
//
#include <hip/hip_runtime.h>
#include <math.h>

#define BB 4
#define NN 2048
#define KNN 20

typedef _Float16 f16x8 __attribute__((ext_vector_type(8)));
typedef _Float16 f16x4 __attribute__((ext_vector_type(4)));
typedef float f32x4 __attribute__((ext_vector_type(4)));

// ---------------------------------------------------------------------------
// KNN: one WAVE per point (unchanged — bit-exact ordering vs lax.top_k(-d2)).
// ---------------------------------------------------------------------------
__global__ __launch_bounds__(256) void knn_kernel(const float* __restrict__ pc,
                                                  int* __restrict__ idx_out,
                                                  float* __restrict__ rel_out) {
    __shared__ float sx[NN], sy[NN], sz[NN];
    const int tid = threadIdx.x;
    const int b = blockIdx.x / (NN / 4);
    const int grp = blockIdx.x % (NN / 4);
    for (int p = tid; p < NN; p += 256) {
        sx[p] = pc[(size_t)(b * NN + p) * 6 + 0];
        sy[p] = pc[(size_t)(b * NN + p) * 6 + 1];
        sz[p] = pc[(size_t)(b * NN + p) * 6 + 2];
    }
    __syncthreads();
    const int lane = tid & 63;
    const int wv = tid >> 6;
    const int i = grp * 4 + wv;
    const float xi = sx[i], yi = sy[i], zi = sz[i];
    const float sqi = __fadd_rn(__fadd_rn(__fmul_rn(xi, xi), __fmul_rn(yi, yi)), __fmul_rn(zi, zi));
    float d2r[32];
#pragma unroll
    for (int t = 0; t < 32; ++t) {
        int j = t * 64 + lane;
        float xj = sx[j], yj = sy[j], zj = sz[j];
        float sqj = __fadd_rn(__fadd_rn(__fmul_rn(xj, xj), __fmul_rn(yj, yj)), __fmul_rn(zj, zj));
        float dot = __fadd_rn(__fadd_rn(__fmul_rn(xi, xj), __fmul_rn(yi, yj)), __fmul_rn(zi, zj));
        d2r[t] = __fsub_rn(__fadd_rn(sqi, sqj), __fmul_rn(2.0f, dot));
    }
    float lv = -INFINITY; int lj = -1;
    for (int k = 0; k < KNN; ++k) {
        float bv = INFINITY; int bj = 0x7fffffff;
#pragma unroll
        for (int t = 0; t < 32; ++t) {
            int j = t * 64 + lane;
            float v = d2r[t];
            bool gt = (v > lv) || (v == lv && j > lj);
            bool lt = (v < bv) || (v == bv && j < bj);
            if (gt && lt) { bv = v; bj = j; }
        }
#pragma unroll
        for (int m = 32; m >= 1; m >>= 1) {
            float ov = __shfl_xor(bv, m, 64);
            int oj = __shfl_xor(bj, m, 64);
            if (ov < bv || (ov == bv && oj < bj)) { bv = ov; bj = oj; }
        }
        lv = bv; lj = bj;
        if (lane == 0) {
            idx_out[((size_t)(b * NN + i)) * KNN + k] = bj;
            size_t ro = (((size_t)(b * NN + i)) * KNN + k) * 3;
            rel_out[ro + 0] = __fsub_rn(sx[bj], xi);
            rel_out[ro + 1] = __fsub_rn(sy[bj], yi);
            rel_out[ro + 2] = __fsub_rn(sz[bj], zi);
        }
    }
}

// ---------------------------------------------------------------------------
// Per-layer taylor: t[o] = b1[o] + sum_q w1[o,q]*terms[q], layout (B*N*K, 3)
// ---------------------------------------------------------------------------
__global__ __launch_bounds__(256) void taylor_kernel(const float* __restrict__ rel,
                                                     const float* __restrict__ w1,
                                                     const float* __restrict__ b1,
                                                     float* __restrict__ ty) {
    int t = blockIdx.x * 256 + threadIdx.x;
    if (t >= BB * NN * KNN) return;
    float X = rel[(size_t)t * 3 + 0], Y = rel[(size_t)t * 3 + 1], Z = rel[(size_t)t * 3 + 2];
    float tm[20];
    tm[0] = 1.f; tm[1] = X; tm[2] = Y; tm[3] = Z;
    tm[4] = X * Y; tm[5] = X * Z; tm[6] = Y * Z;
    tm[7] = X * X; tm[8] = Y * Y; tm[9] = Z * Z;
    tm[10] = X * X * Y; tm[11] = X * X * Z; tm[12] = X * Y * Y; tm[13] = Y * Y * Z;
    tm[14] = X * Z * Z; tm[15] = Y * Z * Z; tm[16] = X * Y * Z;
    tm[17] = X * X * X; tm[18] = Y * Y * Y; tm[19] = Z * Z * Z;
#pragma unroll
    for (int o = 0; o < 3; ++o) {
        float a = b1[o];
#pragma unroll
        for (int q = 0; q < 20; ++q) a += w1[o * 20 + q] * tm[q];
        ty[(size_t)t * 3 + o] = a;
    }
}

// ---------------------------------------------------------------------------
// Weight prep: w2 (COUT, CIN*3, 20) f32 -> split f16 hi/lo, layout
// [k][oc][kk] with kk = o*CIN + c, padded to CK3P (zeros).
// ---------------------------------------------------------------------------
__global__ __launch_bounds__(256) void wsplit_kernel(const float* __restrict__ w2,
                                                     _Float16* __restrict__ wh,
                                                     _Float16* __restrict__ wl,
                                                     int COUT, int CIN, int CK3P) {
    int e = blockIdx.x * 256 + threadIdx.x;
    int total = KNN * COUT * CK3P;
    if (e >= total) return;
    int kk = e % CK3P;
    int oc = (e / CK3P) % COUT;
    int k = e / (CK3P * COUT);
    float x = 0.f;
    int CK3 = CIN * 3;
    if (kk < CK3) {
        int o = kk / CIN, c = kk % CIN;
        x = w2[((size_t)oc * CK3 + c * 3 + o) * KNN + k];
    }
    _Float16 h = (_Float16)x;
    wh[e] = h;
    wl[e] = (_Float16)(x - (float)h);
}

// ---------------------------------------------------------------------------
// SpiderConv via MFMA, split-f16 3-pass (AhBh + AhBl + AlBh).
// C[oc,n] = sum_{k,kk=(o,c)} W[k,oc,kk] * (fin[idx[n,k],c] * ty[n,k,o])
// Block: OT x NT output tile; 4 waves of (FM*16) x (FN*16).
// LDS rows padded +8 f16 -> stride/16 odd -> uniform bank spread on b128.
// ---------------------------------------------------------------------------
template <int CIN, int COUT, int CK3P, int KCH, int OT, int NT, int FM, int FN, int WMW>
__global__ __launch_bounds__(256) void convm_kernel(const float* __restrict__ fin,
                                                    const int* __restrict__ idx,
                                                    const float* __restrict__ tyg,
                                                    const _Float16* __restrict__ wh,
                                                    const _Float16* __restrict__ wl,
                                                    const float* __restrict__ b2,
                                                    float* __restrict__ fout) {
    static_assert(NT == 64, "staging assumes NT==64");
    constexpr int NCH = CK3P / KCH;
    constexpr int SR = KCH + 8;
    constexpr int WNW = 4 / WMW;
    constexpr int OCT = COUT / OT;
    constexpr int NTL = NN / NT;
    __shared__ _Float16 Ah[OT * SR], Al[OT * SR], Bh[NT * SR], Bl[NT * SR];
    __shared__ float tylb[2][3][NT];
    const int tid = threadIdx.x;
    const int lane = tid & 63;
    const int wid = tid >> 6;
    const int wm = wid / WNW;
    const int wn = wid % WNW;
    const int bid = blockIdx.x;
    const int oct = bid % OCT;
    const int ntl = (bid / OCT) % NTL;
    const int b = bid / (OCT * NTL);
    const int n0 = ntl * NT, oc0 = oct * OT;
    const size_t brow = (size_t)b * NN;
    const int nst = tid & 63;

    f32x4 acc[FM][FN];
#pragma unroll
    for (int fm = 0; fm < FM; ++fm)
#pragma unroll
        for (int fn = 0; fn < FN; ++fn) acc[fm][fn] = (f32x4){0.f, 0.f, 0.f, 0.f};

    if (tid < 3 * NT) {
        int o = tid / NT, n = tid % NT;
        tylb[0][o][n] = tyg[((brow + n0 + n) * KNN + 0) * 3 + o];
    }

    for (int k = 0; k < KNN; ++k) {
        const int kb = k & 1;
        const int j = idx[(brow + n0 + nst) * KNN + k];
        const size_t finrow = (brow + j) * CIN;
#pragma unroll 1
        for (int ch = 0; ch < NCH; ++ch) {
            __syncthreads();
            // ---- stage A (weights, pre-split) ----
            constexpr int AELEM = OT * KCH / 8;
            for (int e = tid; e < AELEM; e += 256) {
                int row = e / (KCH / 8), c8 = e % (KCH / 8);
                size_t src = ((size_t)k * COUT + oc0 + row) * CK3P + ch * KCH + c8 * 8;
                *reinterpret_cast<f16x8*>(&Ah[row * SR + c8 * 8]) =
                    *reinterpret_cast<const f16x8*>(&wh[src]);
                *reinterpret_cast<f16x8*>(&Al[row * SR + c8 * 8]) =
                    *reinterpret_cast<const f16x8*>(&wl[src]);
            }
            // ---- stage B (gather * taylor, split to f16 hi/lo) ----
            if constexpr (CIN >= 16) {
                constexpr int QN = KCH / 16;
#pragma unroll
                for (int q = 0; q < QN; ++q) {
                    int c4 = (tid >> 6) + q * 4;
                    int kkg = ch * KCH + c4 * 4;
                    int o = kkg / CIN, c = kkg - o * CIN;
                    float4 f = *reinterpret_cast<const float4*>(&fin[finrow + c]);
                    float t = tylb[kb][o][nst];
                    float x0 = f.x * t, x1 = f.y * t, x2 = f.z * t, x3 = f.w * t;
                    _Float16 h0 = (_Float16)x0, h1 = (_Float16)x1;
                    _Float16 h2 = (_Float16)x2, h3 = (_Float16)x3;
                    f16x4 hv = {h0, h1, h2, h3};
                    f16x4 lvv = {(_Float16)(x0 - (float)h0), (_Float16)(x1 - (float)h1),
                                 (_Float16)(x2 - (float)h2), (_Float16)(x3 - (float)h3)};
                    *reinterpret_cast<f16x4*>(&Bh[nst * SR + c4 * 4]) = hv;
                    *reinterpret_cast<f16x4*>(&Bl[nst * SR + c4 * 4]) = lvv;
                }
            } else {
                for (int e = tid; e < NT * KCH; e += 256) {
                    int n = e & 63;
                    int kk = e >> 6;
                    _Float16 hv = (_Float16)0.f, lvv = (_Float16)0.f;
                    if (kk < CIN * 3) {
                        int o = kk / CIN, c = kk % CIN;
                        float x = fin[finrow + c] * tylb[kb][o][n];
                        hv = (_Float16)x;
                        lvv = (_Float16)(x - (float)hv);
                    }
                    Bh[n * SR + kk] = hv;
                    Bl[n * SR + kk] = lvv;
                }
            }
            // prefetch next-k taylor slice into the other buffer
            if (ch == NCH - 1 && k < KNN - 1 && tid < 3 * NT) {
                int o = tid / NT, n = tid % NT;
                tylb[kb ^ 1][o][n] = tyg[((brow + n0 + n) * KNN + (k + 1)) * 3 + o];
            }
            __syncthreads();
            // ---- MFMA over this K-chunk, 3 passes ----
#pragma unroll
            for (int kc = 0; kc < KCH / 32; ++kc) {
                const int cofs = kc * 32 + (lane >> 4) * 8;
                f16x8 ah[FM], al[FM], bh[FN], bl[FN];
#pragma unroll
                for (int fm = 0; fm < FM; ++fm) {
                    int row = wm * FM * 16 + fm * 16 + (lane & 15);
                    ah[fm] = *reinterpret_cast<const f16x8*>(&Ah[row * SR + cofs]);
                    al[fm] = *reinterpret_cast<const f16x8*>(&Al[row * SR + cofs]);
                }
#pragma unroll
                for (int fn = 0; fn < FN; ++fn) {
                    int row = wn * FN * 16 + fn * 16 + (lane & 15);
                    bh[fn] = *reinterpret_cast<const f16x8*>(&Bh[row * SR + cofs]);
                    bl[fn] = *reinterpret_cast<const f16x8*>(&Bl[row * SR + cofs]);
                }
#pragma unroll
                for (int fm = 0; fm < FM; ++fm)
#pragma unroll
                    for (int fn = 0; fn < FN; ++fn) {
                        acc[fm][fn] = __builtin_amdgcn_mfma_f32_16x16x32_f16(
                            ah[fm], bh[fn], acc[fm][fn], 0, 0, 0);
                        acc[fm][fn] = __builtin_amdgcn_mfma_f32_16x16x32_f16(
                            ah[fm], bl[fn], acc[fm][fn], 0, 0, 0);
                        acc[fm][fn] = __builtin_amdgcn_mfma_f32_16x16x32_f16(
                            al[fm], bh[fn], acc[fm][fn], 0, 0, 0);
                    }
            }
        }
    }
    // ---- epilogue: bias + relu, D layout col=lane&15, row=(lane>>4)*4+r ----
#pragma unroll
    for (int fm = 0; fm < FM; ++fm) {
        const int ocb = oc0 + wm * FM * 16 + fm * 16 + (lane >> 4) * 4;
        const float bs0 = b2[ocb + 0], bs1 = b2[ocb + 1];
        const float bs2 = b2[ocb + 2], bs3 = b2[ocb + 3];
#pragma unroll
        for (int fn = 0; fn < FN; ++fn) {
            int nnn = n0 + wn * FN * 16 + fn * 16 + (lane & 15);
            float4 o4;
            o4.x = fmaxf(acc[fm][fn][0] + bs0, 0.f);
            o4.y = fmaxf(acc[fm][fn][1] + bs1, 0.f);
            o4.z = fmaxf(acc[fm][fn][2] + bs2, 0.f);
            o4.w = fmaxf(acc[fm][fn][3] + bs3, 0.f);
            *reinterpret_cast<float4*>(&fout[(brow + nnn) * COUT + ocb]) = o4;
        }
    }
}

// ---------------------------------------------------------------------------
// top-2 over N per (b, channel); cat order f1|f2|f3|f4 -> out (B, 480*2)
// ---------------------------------------------------------------------------
__global__ __launch_bounds__(256) void top2_kernel(const float* __restrict__ f1,
                                                   const float* __restrict__ f2,
                                                   const float* __restrict__ f3,
                                                   const float* __restrict__ f4,
                                                   float* __restrict__ out) {
    __shared__ float m1s[256], m2s[256];
    const int bid = blockIdx.x;
    const int b = bid / 480;
    const int ch = bid % 480;
    const float* f; int C, c;
    if (ch < 32)       { f = f1; C = 32;  c = ch; }
    else if (ch < 96)  { f = f2; C = 64;  c = ch - 32; }
    else if (ch < 224) { f = f3; C = 128; c = ch - 96; }
    else               { f = f4; C = 256; c = ch - 224; }
    float m1 = -INFINITY, m2 = -INFINITY;
    for (int n = threadIdx.x; n < NN; n += 256) {
        float v = f[((size_t)(b * NN) + n) * C + c];
        if (v > m1) { m2 = m1; m1 = v; }
        else if (v > m2) m2 = v;
    }
    m1s[threadIdx.x] = m1; m2s[threadIdx.x] = m2;
    __syncthreads();
    for (int s = 128; s > 0; s >>= 1) {
        if (threadIdx.x < s) {
            float a1 = m1s[threadIdx.x], a2 = m2s[threadIdx.x];
            float c1 = m1s[threadIdx.x + s], c2 = m2s[threadIdx.x + s];
            m1s[threadIdx.x] = fmaxf(a1, c1);
            m2s[threadIdx.x] = fmaxf(fminf(a1, c1), fmaxf(a2, c2));
        }
        __syncthreads();
    }
    if (threadIdx.x == 0) {
        out[(size_t)b * 960 + ch * 2 + 0] = m1s[0];
        out[(size_t)b * 960 + ch * 2 + 1] = m2s[0];
    }
}

extern "C" void kernel_launch(void* const* d_in, const int* in_sizes, int n_in,
                              void* d_out, int out_size, void* d_ws, size_t ws_size,
                              hipStream_t stream) {
    const float* pc = (const float*)d_in[0];
    const float *w1[4], *b1[4], *w2[4], *b2[4];
    for (int l = 0; l < 4; ++l) {
        w1[l] = (const float*)d_in[1 + 4 * l];
        b1[l] = (const float*)d_in[2 + 4 * l];
        w2[l] = (const float*)d_in[3 + 4 * l];
        b2[l] = (const float*)d_in[4 + 4 * l];
    }
    char* ws = (char*)d_ws;
    size_t off = 0;
    auto alloc = [&](size_t bytes) -> void* {
        void* p = ws + off;
        off = (off + bytes + 255) & ~(size_t)255;
        return p;
    };
    int* idxb       = (int*)alloc((size_t)BB * NN * KNN * 4);
    float* rel      = (float*)alloc((size_t)BB * NN * KNN * 3 * 4);
    float* tyb      = (float*)alloc((size_t)BB * NN * KNN * 3 * 4);
    _Float16* whb   = (_Float16*)alloc((size_t)KNN * 256 * 384 * 2);
    _Float16* wlb   = (_Float16*)alloc((size_t)KNN * 256 * 384 * 2);
    float* f1       = (float*)alloc((size_t)BB * NN * 32 * 4);
    float* f2       = (float*)alloc((size_t)BB * NN * 64 * 4);
    float* f3       = (float*)alloc((size_t)BB * NN * 128 * 4);
    float* f4       = (float*)alloc((size_t)BB * NN * 256 * 4);

    knn_kernel<<<BB * NN / 4, 256, 0, stream>>>(pc, idxb, rel);

    const int tgrid = (BB * NN * KNN + 255) / 256;

    // layer 0: cin=6, cout=32, CK3P=32 (padded)
    taylor_kernel<<<tgrid, 256, 0, stream>>>(rel, w1[0], b1[0], tyb);
    wsplit_kernel<<<(KNN * 32 * 32 + 255) / 256, 256, 0, stream>>>(w2[0], whb, wlb, 32, 6, 32);
    convm_kernel<6, 32, 32, 32, 32, 64, 2, 1, 1>
        <<<BB * (NN / 64) * 1, 256, 0, stream>>>(pc, idxb, tyb, whb, wlb, b2[0], f1);

    // layer 1: cin=32, cout=64, CK3=96
    taylor_kernel<<<tgrid, 256, 0, stream>>>(rel, w1[1], b1[1], tyb);
    wsplit_kernel<<<(KNN * 64 * 96 + 255) / 256, 256, 0, stream>>>(w2[1], whb, wlb, 64, 32, 96);
    convm_kernel<32, 64, 96, 96, 64, 64, 2, 2, 2>
        <<<BB * (NN / 64) * 1, 256, 0, stream>>>(f1, idxb, tyb, whb, wlb, b2[1], f2);

    // layer 2: cin=64, cout=128, CK3=192
    taylor_kernel<<<tgrid, 256, 0, stream>>>(rel, w1[2], b1[2], tyb);
    wsplit_kernel<<<(KNN * 128 * 192 + 255) / 256, 256, 0, stream>>>(w2[2], whb, wlb, 128, 64, 192);
    convm_kernel<64, 128, 192, 64, 64, 64, 2, 2, 2>
        <<<BB * (NN / 64) * 2, 256, 0, stream>>>(f2, idxb, tyb, whb, wlb, b2[2], f3);

    // layer 3: cin=128, cout=256, CK3=384
    taylor_kernel<<<tgrid, 256, 0, stream>>>(rel, w1[3], b1[3], tyb);
    wsplit_kernel<<<(KNN * 256 * 384 + 255) / 256, 256, 0, stream>>>(w2[3], whb, wlb, 256, 128, 384);
    convm_kernel<128, 256, 384, 64, 64, 64, 2, 2, 2>
        <<<BB * (NN / 64) * 4, 256, 0, stream>>>(f3, idxb, tyb, whb, wlb, b2[3], f4);

    top2_kernel<<<BB * 480, 256, 0, stream>>>(f1, f2, f3, f4, (float*)d_out);
}

// Round 4
// 522.701 us; speedup vs baseline: 4.9809x; 1.1310x over previous
//
#include <hip/hip_runtime.h>
#include <math.h>

#define BB 4
#define NN 2048
#define KNN 20

typedef _Float16 f16x8 __attribute__((ext_vector_type(8)));
typedef _Float16 f16x4 __attribute__((ext_vector_type(4)));
typedef float f32x4 __attribute__((ext_vector_type(4)));

// ---------------------------------------------------------------------------
// KNN: one WAVE per point (bit-exact ordering vs lax.top_k(-d2)).
// ---------------------------------------------------------------------------
__global__ __launch_bounds__(256) void knn_kernel(const float* __restrict__ pc,
                                                  int* __restrict__ idx_out,
                                                  float* __restrict__ rel_out) {
    __shared__ float sx[NN], sy[NN], sz[NN];
    const int tid = threadIdx.x;
    const int b = blockIdx.x / (NN / 4);
    const int grp = blockIdx.x % (NN / 4);
    for (int p = tid; p < NN; p += 256) {
        sx[p] = pc[(size_t)(b * NN + p) * 6 + 0];
        sy[p] = pc[(size_t)(b * NN + p) * 6 + 1];
        sz[p] = pc[(size_t)(b * NN + p) * 6 + 2];
    }
    __syncthreads();
    const int lane = tid & 63;
    const int wv = tid >> 6;
    const int i = grp * 4 + wv;
    const float xi = sx[i], yi = sy[i], zi = sz[i];
    const float sqi = __fadd_rn(__fadd_rn(__fmul_rn(xi, xi), __fmul_rn(yi, yi)), __fmul_rn(zi, zi));
    float d2r[32];
#pragma unroll
    for (int t = 0; t < 32; ++t) {
        int j = t * 64 + lane;
        float xj = sx[j], yj = sy[j], zj = sz[j];
        float sqj = __fadd_rn(__fadd_rn(__fmul_rn(xj, xj), __fmul_rn(yj, yj)), __fmul_rn(zj, zj));
        float dot = __fadd_rn(__fadd_rn(__fmul_rn(xi, xj), __fmul_rn(yi, yj)), __fmul_rn(zi, zj));
        d2r[t] = __fsub_rn(__fadd_rn(sqi, sqj), __fmul_rn(2.0f, dot));
    }
    float lv = -INFINITY; int lj = -1;
    for (int k = 0; k < KNN; ++k) {
        float bv = INFINITY; int bj = 0x7fffffff;
#pragma unroll
        for (int t = 0; t < 32; ++t) {
            int j = t * 64 + lane;
            float v = d2r[t];
            bool gt = (v > lv) || (v == lv && j > lj);
            bool lt = (v < bv) || (v == bv && j < bj);
            if (gt && lt) { bv = v; bj = j; }
        }
#pragma unroll
        for (int m = 32; m >= 1; m >>= 1) {
            float ov = __shfl_xor(bv, m, 64);
            int oj = __shfl_xor(bj, m, 64);
            if (ov < bv || (ov == bv && oj < bj)) { bv = ov; bj = oj; }
        }
        lv = bv; lj = bj;
        if (lane == 0) {
            idx_out[((size_t)(b * NN + i)) * KNN + k] = bj;
            size_t ro = (((size_t)(b * NN + i)) * KNN + k) * 3;
            rel_out[ro + 0] = __fsub_rn(sx[bj], xi);
            rel_out[ro + 1] = __fsub_rn(sy[bj], yi);
            rel_out[ro + 2] = __fsub_rn(sz[bj], zi);
        }
    }
}

// ---------------------------------------------------------------------------
// Taylor: t[o] = b1[o] + sum_q w1[o,q]*terms[q], layout (B,N,K,3)
// ---------------------------------------------------------------------------
__global__ __launch_bounds__(256) void taylor_kernel(const float* __restrict__ rel,
                                                     const float* __restrict__ w1,
                                                     const float* __restrict__ b1,
                                                     float* __restrict__ ty) {
    int t = blockIdx.x * 256 + threadIdx.x;
    if (t >= BB * NN * KNN) return;
    float X = rel[(size_t)t * 3 + 0], Y = rel[(size_t)t * 3 + 1], Z = rel[(size_t)t * 3 + 2];
    float tm[20];
    tm[0] = 1.f; tm[1] = X; tm[2] = Y; tm[3] = Z;
    tm[4] = X * Y; tm[5] = X * Z; tm[6] = Y * Z;
    tm[7] = X * X; tm[8] = Y * Y; tm[9] = Z * Z;
    tm[10] = X * X * Y; tm[11] = X * X * Z; tm[12] = X * Y * Y; tm[13] = Y * Y * Z;
    tm[14] = X * Z * Z; tm[15] = Y * Z * Z; tm[16] = X * Y * Z;
    tm[17] = X * X * X; tm[18] = Y * Y * Y; tm[19] = Z * Z * Z;
#pragma unroll
    for (int o = 0; o < 3; ++o) {
        float a = b1[o];
#pragma unroll
        for (int q = 0; q < 20; ++q) a += w1[o * 20 + q] * tm[q];
        ty[(size_t)t * 3 + o] = a;
    }
}

// ---------------------------------------------------------------------------
// Weight prep: w2 (COUT, CIN*3, 20) f32 -> f16 in MFMA-fragment-linear order:
// wf[(((k*OCB + ocb)*KCB + kcb)*64 + lane)*8 + i], where
//   oc = ocb*16 + (lane&15), kk = kcb*32 + (lane>>4)*8 + i,
//   o = kk / CPAD, c = kk % CPAD (zero if o>=3 or c>=CIN).
// One thread per output element -> coalesced 2B writes.
// ---------------------------------------------------------------------------
__global__ __launch_bounds__(256) void wsplit2_kernel(const float* __restrict__ w2,
                                                      _Float16* __restrict__ wf,
                                                      int COUT, int CIN, int CPAD,
                                                      int OCB, int KCB, int total) {
    int e = blockIdx.x * 256 + threadIdx.x;
    if (e >= total) return;
    int i = e & 7;
    int lane = (e >> 3) & 63;
    int fi = e >> 9;                 // frag index = (k*OCB + ocb)*KCB + kcb
    int kcb = fi % KCB;
    int ocb = (fi / KCB) % OCB;
    int k = fi / (KCB * OCB);
    int oc = ocb * 16 + (lane & 15);
    int kk = kcb * 32 + (lane >> 4) * 8 + i;
    int o = kk / CPAD, c = kk % CPAD;
    float x = 0.f;
    if (o < 3 && c < CIN)
        x = w2[((size_t)oc * (CIN * 3) + c * 3 + o) * KNN + k];
    wf[e] = (_Float16)x;
}

// ---------------------------------------------------------------------------
// SpiderConv via MFMA, single-pass f16.
// Block = COUT x NT output tile (all oc in one block -> B built once).
// 4 waves arranged WM x WN; wave tile = (FM*16) x (FN*16).
// A: global->reg from fragment-linear wf. B: LDS, built per k from gathers.
// ---------------------------------------------------------------------------
template <int CIN, int COUT, int CK3P, int NT, int WM, int WN, int FM, int FN, bool L0S>
__global__ __launch_bounds__(256) void convm_kernel(const float* __restrict__ fin,
                                                    const int* __restrict__ idx,
                                                    const float* __restrict__ tyg,
                                                    const _Float16* __restrict__ wf,
                                                    const float* __restrict__ b2,
                                                    float* __restrict__ fout) {
    static_assert(WM * FM * 16 == COUT, "oc tiling");
    static_assert(WN * FN * 16 == NT, "n tiling");
    static_assert(WM * WN == 4, "4 waves");
    constexpr int SR = CK3P + 8;          // f16 elems; stride/16B odd
    constexpr int KCB = CK3P / 32;
    constexpr int OCB = COUT / 16;
    constexpr int Q = L0S ? 1 : (CIN / 32);   // float4 gathers per thread
    __shared__ _Float16 Bs[NT * SR];
    __shared__ float tyt[NT][60];
    __shared__ int idxt[NT][KNN];

    const int tid = threadIdx.x;
    const int lane = tid & 63;
    const int wid = tid >> 6;
    const int wm = wid / WN;
    const int wn = wid % WN;
    const int ntl = blockIdx.x % (NN / NT);
    const int b = blockIdx.x / (NN / NT);
    const int n0 = ntl * NT;
    const size_t brow = (size_t)b * NN;

    // ---- preload idx + taylor tiles (coalesced) ----
    for (int e = tid; e < NT * KNN; e += 256) {
        int n = e / KNN, kk = e % KNN;
        idxt[n][kk] = idx[(brow + n0 + n) * KNN + kk];
    }
    for (int e = tid; e < NT * 60; e += 256) {
        int n = e / 60, q = e % 60;
        tyt[n][q] = tyg[(brow + n0 + n) * 60 + q];
    }
    __syncthreads();

    // ---- gather state ----
    const int nrow = L0S ? (tid & 63) : (tid >> 3);
    const int S_ = tid & 7;
    const int oL0 = tid >> 6;
    float4 g[Q];
    float2 r0, r1, r2;

    auto issue_gather = [&](int kk) {
        if constexpr (L0S) {
            if (tid < 192) {
                int j = idxt[nrow][kk];
                const float* p = fin + (brow + j) * CIN;
                r0 = *reinterpret_cast<const float2*>(p + 0);
                r1 = *reinterpret_cast<const float2*>(p + 2);
                r2 = *reinterpret_cast<const float2*>(p + 4);
            }
        } else {
            int j = idxt[nrow][kk];
            const float* p = fin + (brow + j) * CIN + S_ * 4;
#pragma unroll
            for (int q = 0; q < Q; ++q)
                g[q] = *reinterpret_cast<const float4*>(p + q * 32);
        }
    };
    issue_gather(0);

    f32x4 acc[FM][FN];
#pragma unroll
    for (int fm = 0; fm < FM; ++fm)
#pragma unroll
        for (int fn = 0; fn < FN; ++fn) acc[fm][fn] = (f32x4){0.f, 0.f, 0.f, 0.f};

    for (int k = 0; k < KNN; ++k) {
        __syncthreads();   // previous MFMA done reading Bs
        // ---- build B tile for this k ----
        if constexpr (L0S) {
            if (tid < 192) {
                float t = tyt[nrow][k * 3 + oL0];
                f16x8 hv;
                hv[0] = (_Float16)(r0.x * t); hv[1] = (_Float16)(r0.y * t);
                hv[2] = (_Float16)(r1.x * t); hv[3] = (_Float16)(r1.y * t);
                hv[4] = (_Float16)(r2.x * t); hv[5] = (_Float16)(r2.y * t);
                hv[6] = (_Float16)0.f; hv[7] = (_Float16)0.f;
                *reinterpret_cast<f16x8*>(&Bs[nrow * SR + oL0 * 8]) = hv;
                if (oL0 == 0) {
                    f16x8 z = {};
                    *reinterpret_cast<f16x8*>(&Bs[nrow * SR + 24]) = z;
                }
            }
        } else {
            float tv0 = tyt[nrow][k * 3 + 0];
            float tv1 = tyt[nrow][k * 3 + 1];
            float tv2 = tyt[nrow][k * 3 + 2];
#pragma unroll
            for (int o = 0; o < 3; ++o) {
                float t = (o == 0) ? tv0 : (o == 1) ? tv1 : tv2;
#pragma unroll
                for (int q = 0; q < Q; ++q) {
                    f16x4 hv;
                    hv[0] = (_Float16)(g[q].x * t);
                    hv[1] = (_Float16)(g[q].y * t);
                    hv[2] = (_Float16)(g[q].z * t);
                    hv[3] = (_Float16)(g[q].w * t);
                    *reinterpret_cast<f16x4*>(&Bs[nrow * SR + o * CIN + S_ * 4 + q * 32]) = hv;
                }
            }
        }
        __syncthreads();   // B ready
        if (k + 1 < KNN) issue_gather(k + 1);  // overlap next gather with MFMA
        // ---- MFMA over full CK3P ----
#pragma unroll 4
        for (int kcb = 0; kcb < KCB; ++kcb) {
            f16x8 af[FM], bf[FN];
#pragma unroll
            for (int fm = 0; fm < FM; ++fm) {
                size_t fidx = (((size_t)k * OCB + wm * FM + fm) * KCB + kcb) * 64 + lane;
                af[fm] = *reinterpret_cast<const f16x8*>(&wf[fidx * 8]);
            }
#pragma unroll
            for (int fn = 0; fn < FN; ++fn) {
                int row = wn * FN * 16 + fn * 16 + (lane & 15);
                bf[fn] = *reinterpret_cast<const f16x8*>(
                    &Bs[row * SR + kcb * 32 + (lane >> 4) * 8]);
            }
#pragma unroll
            for (int fm = 0; fm < FM; ++fm)
#pragma unroll
                for (int fn = 0; fn < FN; ++fn)
                    acc[fm][fn] = __builtin_amdgcn_mfma_f32_16x16x32_f16(
                        af[fm], bf[fn], acc[fm][fn], 0, 0, 0);
        }
    }
    // ---- epilogue: bias + relu; D: col(lane&15)=n, row=(lane>>4)*4+r = oc ----
#pragma unroll
    for (int fm = 0; fm < FM; ++fm) {
        const int ocb = wm * FM * 16 + fm * 16 + (lane >> 4) * 4;
        const float bs0 = b2[ocb + 0], bs1 = b2[ocb + 1];
        const float bs2 = b2[ocb + 2], bs3 = b2[ocb + 3];
#pragma unroll
        for (int fn = 0; fn < FN; ++fn) {
            int nnn = n0 + wn * FN * 16 + fn * 16 + (lane & 15);
            float4 o4;
            o4.x = fmaxf(acc[fm][fn][0] + bs0, 0.f);
            o4.y = fmaxf(acc[fm][fn][1] + bs1, 0.f);
            o4.z = fmaxf(acc[fm][fn][2] + bs2, 0.f);
            o4.w = fmaxf(acc[fm][fn][3] + bs3, 0.f);
            *reinterpret_cast<float4*>(&fout[(brow + nnn) * COUT + ocb]) = o4;
        }
    }
}

// ---------------------------------------------------------------------------
// top-2 over N per (b, channel); cat order f1|f2|f3|f4 -> out (B, 480*2)
// ---------------------------------------------------------------------------
__global__ __launch_bounds__(256) void top2_kernel(const float* __restrict__ f1,
                                                   const float* __restrict__ f2,
                                                   const float* __restrict__ f3,
                                                   const float* __restrict__ f4,
                                                   float* __restrict__ out) {
    __shared__ float m1s[256], m2s[256];
    const int bid = blockIdx.x;
    const int b = bid / 480;
    const int ch = bid % 480;
    const float* f; int C, c;
    if (ch < 32)       { f = f1; C = 32;  c = ch; }
    else if (ch < 96)  { f = f2; C = 64;  c = ch - 32; }
    else if (ch < 224) { f = f3; C = 128; c = ch - 96; }
    else               { f = f4; C = 256; c = ch - 224; }
    float m1 = -INFINITY, m2 = -INFINITY;
    for (int n = threadIdx.x; n < NN; n += 256) {
        float v = f[((size_t)(b * NN) + n) * C + c];
        if (v > m1) { m2 = m1; m1 = v; }
        else if (v > m2) m2 = v;
    }
    m1s[threadIdx.x] = m1; m2s[threadIdx.x] = m2;
    __syncthreads();
    for (int s = 128; s > 0; s >>= 1) {
        if (threadIdx.x < s) {
            float a1 = m1s[threadIdx.x], a2 = m2s[threadIdx.x];
            float c1 = m1s[threadIdx.x + s], c2 = m2s[threadIdx.x + s];
            m1s[threadIdx.x] = fmaxf(a1, c1);
            m2s[threadIdx.x] = fmaxf(fminf(a1, c1), fmaxf(a2, c2));
        }
        __syncthreads();
    }
    if (threadIdx.x == 0) {
        out[(size_t)b * 960 + ch * 2 + 0] = m1s[0];
        out[(size_t)b * 960 + ch * 2 + 1] = m2s[0];
    }
}

extern "C" void kernel_launch(void* const* d_in, const int* in_sizes, int n_in,
                              void* d_out, int out_size, void* d_ws, size_t ws_size,
                              hipStream_t stream) {
    const float* pc = (const float*)d_in[0];
    const float *w1[4], *b1[4], *w2[4], *b2[4];
    for (int l = 0; l < 4; ++l) {
        w1[l] = (const float*)d_in[1 + 4 * l];
        b1[l] = (const float*)d_in[2 + 4 * l];
        w2[l] = (const float*)d_in[3 + 4 * l];
        b2[l] = (const float*)d_in[4 + 4 * l];
    }
    char* ws = (char*)d_ws;
    size_t off = 0;
    auto alloc = [&](size_t bytes) -> void* {
        void* p = ws + off;
        off = (off + bytes + 255) & ~(size_t)255;
        return p;
    };
    int* idxb     = (int*)alloc((size_t)BB * NN * KNN * 4);
    float* rel    = (float*)alloc((size_t)BB * NN * KNN * 3 * 4);
    float* tyb    = (float*)alloc((size_t)BB * NN * KNN * 3 * 4);
    _Float16* wfb = (_Float16*)alloc((size_t)KNN * 16 * 12 * 64 * 8 * 2);
    float* f1     = (float*)alloc((size_t)BB * NN * 32 * 4);
    float* f2     = (float*)alloc((size_t)BB * NN * 64 * 4);
    float* f3     = (float*)alloc((size_t)BB * NN * 128 * 4);
    float* f4     = (float*)alloc((size_t)BB * NN * 256 * 4);

    knn_kernel<<<BB * NN / 4, 256, 0, stream>>>(pc, idxb, rel);

    const int tgrid = (BB * NN * KNN + 255) / 256;

    // layer 0: cin=6 (CPAD=8), cout=32, CK3P=32
    taylor_kernel<<<tgrid, 256, 0, stream>>>(rel, w1[0], b1[0], tyb);
    {
        int total = KNN * 2 * 1 * 64 * 8;
        wsplit2_kernel<<<(total + 255) / 256, 256, 0, stream>>>(w2[0], wfb, 32, 6, 8, 2, 1, total);
    }
    convm_kernel<6, 32, 32, 64, 2, 2, 1, 2, true>
        <<<BB * (NN / 64), 256, 0, stream>>>(pc, idxb, tyb, wfb, b2[0], f1);

    // layer 1: cin=32, cout=64, CK3P=96
    taylor_kernel<<<tgrid, 256, 0, stream>>>(rel, w1[1], b1[1], tyb);
    {
        int total = KNN * 4 * 3 * 64 * 8;
        wsplit2_kernel<<<(total + 255) / 256, 256, 0, stream>>>(w2[1], wfb, 64, 32, 32, 4, 3, total);
    }
    convm_kernel<32, 64, 96, 32, 4, 1, 1, 2, false>
        <<<BB * (NN / 32), 256, 0, stream>>>(f1, idxb, tyb, wfb, b2[1], f2);

    // layer 2: cin=64, cout=128, CK3P=192
    taylor_kernel<<<tgrid, 256, 0, stream>>>(rel, w1[2], b1[2], tyb);
    {
        int total = KNN * 8 * 6 * 64 * 8;
        wsplit2_kernel<<<(total + 255) / 256, 256, 0, stream>>>(w2[2], wfb, 128, 64, 64, 8, 6, total);
    }
    convm_kernel<64, 128, 192, 32, 4, 1, 2, 2, false>
        <<<BB * (NN / 32), 256, 0, stream>>>(f2, idxb, tyb, wfb, b2[2], f3);

    // layer 3: cin=128, cout=256, CK3P=384
    taylor_kernel<<<tgrid, 256, 0, stream>>>(rel, w1[3], b1[3], tyb);
    {
        int total = KNN * 16 * 12 * 64 * 8;
        wsplit2_kernel<<<(total + 255) / 256, 256, 0, stream>>>(w2[3], wfb, 256, 128, 128, 16, 12, total);
    }
    convm_kernel<128, 256, 384, 32, 4, 1, 4, 2, false>
        <<<BB * (NN / 32), 256, 0, stream>>>(f3, idxb, tyb, wfb, b2[3], f4);

    top2_kernel<<<BB * 480, 256, 0, stream>>>(f1, f2, f3, f4, (float*)d_out);
}

// Round 5
// 306.267 us; speedup vs baseline: 8.5008x; 1.7067x over previous
//
#include <hip/hip_runtime.h>
#include <math.h>

#define BB 4
#define NN 2048
#define KNN 20

typedef _Float16 f16x8 __attribute__((ext_vector_type(8)));
typedef _Float16 f16x4 __attribute__((ext_vector_type(4)));
typedef float f32x4 __attribute__((ext_vector_type(4)));

// ---------------------------------------------------------------------------
// KNN: one WAVE per point (bit-exact ordering vs lax.top_k(-d2)).
// ---------------------------------------------------------------------------
__global__ __launch_bounds__(256) void knn_kernel(const float* __restrict__ pc,
                                                  int* __restrict__ idx_out,
                                                  float* __restrict__ rel_out) {
    __shared__ float sx[NN], sy[NN], sz[NN];
    const int tid = threadIdx.x;
    const int b = blockIdx.x / (NN / 4);
    const int grp = blockIdx.x % (NN / 4);
    for (int p = tid; p < NN; p += 256) {
        sx[p] = pc[(size_t)(b * NN + p) * 6 + 0];
        sy[p] = pc[(size_t)(b * NN + p) * 6 + 1];
        sz[p] = pc[(size_t)(b * NN + p) * 6 + 2];
    }
    __syncthreads();
    const int lane = tid & 63;
    const int wv = tid >> 6;
    const int i = grp * 4 + wv;
    const float xi = sx[i], yi = sy[i], zi = sz[i];
    const float sqi = __fadd_rn(__fadd_rn(__fmul_rn(xi, xi), __fmul_rn(yi, yi)), __fmul_rn(zi, zi));
    float d2r[32];
#pragma unroll
    for (int t = 0; t < 32; ++t) {
        int j = t * 64 + lane;
        float xj = sx[j], yj = sy[j], zj = sz[j];
        float sqj = __fadd_rn(__fadd_rn(__fmul_rn(xj, xj), __fmul_rn(yj, yj)), __fmul_rn(zj, zj));
        float dot = __fadd_rn(__fadd_rn(__fmul_rn(xi, xj), __fmul_rn(yi, yj)), __fmul_rn(zi, zj));
        d2r[t] = __fsub_rn(__fadd_rn(sqi, sqj), __fmul_rn(2.0f, dot));
    }
    float lv = -INFINITY; int lj = -1;
    for (int k = 0; k < KNN; ++k) {
        float bv = INFINITY; int bj = 0x7fffffff;
#pragma unroll
        for (int t = 0; t < 32; ++t) {
            int j = t * 64 + lane;
            float v = d2r[t];
            bool gt = (v > lv) || (v == lv && j > lj);
            bool lt = (v < bv) || (v == bv && j < bj);
            if (gt && lt) { bv = v; bj = j; }
        }
#pragma unroll
        for (int m = 32; m >= 1; m >>= 1) {
            float ov = __shfl_xor(bv, m, 64);
            int oj = __shfl_xor(bj, m, 64);
            if (ov < bv || (ov == bv && oj < bj)) { bv = ov; bj = oj; }
        }
        lv = bv; lj = bj;
        if (lane == 0) {
            idx_out[((size_t)(b * NN + i)) * KNN + k] = bj;
            size_t ro = (((size_t)(b * NN + i)) * KNN + k) * 3;
            rel_out[ro + 0] = __fsub_rn(sx[bj], xi);
            rel_out[ro + 1] = __fsub_rn(sy[bj], yi);
            rel_out[ro + 2] = __fsub_rn(sz[bj], zi);
        }
    }
}

// ---------------------------------------------------------------------------
// Taylor for ALL 4 layers in one pass: terms computed once per (b,n,k).
// ---------------------------------------------------------------------------
__global__ __launch_bounds__(256) void taylor_all_kernel(
    const float* __restrict__ rel,
    const float* __restrict__ w10, const float* __restrict__ b10, float* __restrict__ ty0,
    const float* __restrict__ w11, const float* __restrict__ b11, float* __restrict__ ty1,
    const float* __restrict__ w12, const float* __restrict__ b12, float* __restrict__ ty2,
    const float* __restrict__ w13, const float* __restrict__ b13, float* __restrict__ ty3) {
    __shared__ float w1s[4][60];
    __shared__ float b1s[4][3];
    const int tid = threadIdx.x;
    if (tid < 240) {
        const float* wp = (tid < 60) ? w10 : (tid < 120) ? w11 : (tid < 180) ? w12 : w13;
        w1s[tid / 60][tid % 60] = wp[tid % 60];
    } else if (tid < 252) {
        int r = tid - 240;
        const float* bp = (r < 3) ? b10 : (r < 6) ? b11 : (r < 9) ? b12 : b13;
        b1s[r / 3][r % 3] = bp[r % 3];
    }
    __syncthreads();
    int t = blockIdx.x * 256 + tid;
    if (t >= BB * NN * KNN) return;
    float X = rel[(size_t)t * 3 + 0], Y = rel[(size_t)t * 3 + 1], Z = rel[(size_t)t * 3 + 2];
    float tm[20];
    tm[0] = 1.f; tm[1] = X; tm[2] = Y; tm[3] = Z;
    tm[4] = X * Y; tm[5] = X * Z; tm[6] = Y * Z;
    tm[7] = X * X; tm[8] = Y * Y; tm[9] = Z * Z;
    tm[10] = X * X * Y; tm[11] = X * X * Z; tm[12] = X * Y * Y; tm[13] = Y * Y * Z;
    tm[14] = X * Z * Z; tm[15] = Y * Z * Z; tm[16] = X * Y * Z;
    tm[17] = X * X * X; tm[18] = Y * Y * Y; tm[19] = Z * Z * Z;
    float* typ[4] = {ty0, ty1, ty2, ty3};
#pragma unroll
    for (int l = 0; l < 4; ++l) {
#pragma unroll
        for (int o = 0; o < 3; ++o) {
            float a = b1s[l][o];
#pragma unroll
            for (int q = 0; q < 20; ++q) a += w1s[l][o * 20 + q] * tm[q];
            typ[l][(size_t)t * 3 + o] = a;
        }
    }
}

// ---------------------------------------------------------------------------
// Weight prep: w2 (COUT, CIN*3, 20) f32 -> f16 in MFMA-fragment-linear order.
// ---------------------------------------------------------------------------
__global__ __launch_bounds__(256) void wsplit2_kernel(const float* __restrict__ w2,
                                                      _Float16* __restrict__ wf,
                                                      int COUT, int CIN, int CPAD,
                                                      int OCB, int KCB, int total) {
    int e = blockIdx.x * 256 + threadIdx.x;
    if (e >= total) return;
    int i = e & 7;
    int lane = (e >> 3) & 63;
    int fi = e >> 9;
    int kcb = fi % KCB;
    int ocb = (fi / KCB) % OCB;
    int k = fi / (KCB * OCB);
    int oc = ocb * 16 + (lane & 15);
    int kk = kcb * 32 + (lane >> 4) * 8 + i;
    int o = kk / CPAD, c = kk % CPAD;
    float x = 0.f;
    if (o < 3 && c < CIN)
        x = w2[((size_t)oc * (CIN * 3) + c * 3 + o) * KNN + k];
    wf[e] = (_Float16)x;
}

// ---------------------------------------------------------------------------
// SpiderConv via MFMA (single-pass f16), k-split partial sums.
// Writes raw f32 partials (no bias/relu) to out + ks*B*N*COUT.
// ---------------------------------------------------------------------------
template <int CIN, int COUT, int CK3P, int NT, int WM, int WN, int FM, int FN,
          int OCT, int KSPLIT, bool L0S>
__global__ __launch_bounds__(256) void convm_kernel(const float* __restrict__ fin,
                                                    const int* __restrict__ idx,
                                                    const float* __restrict__ tyg,
                                                    const _Float16* __restrict__ wf,
                                                    float* __restrict__ out) {
    constexpr int KR = KNN / KSPLIT;
    constexpr int SR = CK3P + 8;
    constexpr int KCB = CK3P / 32;
    constexpr int OCB = COUT / 16;
    constexpr int OCBLK = WM * FM * 16;
    constexpr int NTL = NN / NT;
    constexpr int TPR = 256 / NT;
    constexpr int CQ = L0S ? 1 : CIN / (4 * TPR);
    static_assert(WN * FN * 16 == NT, "n tiling");
    static_assert(OCBLK * OCT == COUT, "oc tiling");
    static_assert(WM * WN == 4, "4 waves");

    __shared__ _Float16 Bs[NT * SR];
    __shared__ float tyt[NT][3 * KR];
    __shared__ int idxt[NT][KR];

    const int tid = threadIdx.x;
    const int lane = tid & 63;
    const int wid = tid >> 6;
    const int wm = wid / WN;
    const int wn = wid % WN;
    int t = blockIdx.x;
    const int ks = t % KSPLIT; t /= KSPLIT;
    const int oct = t % OCT;   t /= OCT;
    const int ntl = t % NTL;   t /= NTL;
    const int b = t;
    const int n0 = ntl * NT;
    const int oc0 = oct * OCBLK;
    const int k0 = ks * KR;
    const size_t brow = (size_t)b * NN;

    for (int e = tid; e < NT * KR; e += 256) {
        int n = e / KR, kk = e % KR;
        idxt[n][kk] = idx[(brow + n0 + n) * KNN + k0 + kk];
    }
    for (int e = tid; e < NT * 3 * KR; e += 256) {
        int n = e / (3 * KR), q = e % (3 * KR);
        tyt[n][q] = tyg[((brow + n0 + n) * KNN + k0) * 3 + q];
    }
    __syncthreads();

    const int nrow = L0S ? (tid & 63) : (tid / TPR);
    const int sub  = L0S ? (tid >> 6) : (tid % TPR);
    float4 g[CQ];
    float2 r0, r1, r2;

    auto issue_gather = [&](int kk) {
        if constexpr (L0S) {
            if (tid < 192) {
                int j = idxt[nrow][kk];
                const float* p = fin + (brow + j) * 6;
                r0 = *reinterpret_cast<const float2*>(p);
                r1 = *reinterpret_cast<const float2*>(p + 2);
                r2 = *reinterpret_cast<const float2*>(p + 4);
            }
        } else {
            int j = idxt[nrow][kk];
            const float* p = fin + (brow + j) * CIN + sub * (CIN / TPR);
#pragma unroll
            for (int q = 0; q < CQ; ++q)
                g[q] = *reinterpret_cast<const float4*>(p + q * 4);
        }
    };
    issue_gather(0);

    f32x4 acc[FM][FN];
#pragma unroll
    for (int fm = 0; fm < FM; ++fm)
#pragma unroll
        for (int fn = 0; fn < FN; ++fn) acc[fm][fn] = (f32x4){0.f, 0.f, 0.f, 0.f};

    auto loadA = [&](int k, int kcb, f16x8* a) {
#pragma unroll
        for (int fm = 0; fm < FM; ++fm) {
            size_t fidx = ((size_t)k * OCB + (oc0 >> 4) + wm * FM + fm) * KCB + kcb;
            a[fm] = *reinterpret_cast<const f16x8*>(&wf[(fidx * 64 + lane) * 8]);
        }
    };
    auto loadB = [&](int kcb, f16x8* bb) {
#pragma unroll
        for (int fn = 0; fn < FN; ++fn) {
            int row = wn * FN * 16 + fn * 16 + (lane & 15);
            bb[fn] = *reinterpret_cast<const f16x8*>(
                &Bs[row * SR + kcb * 32 + (lane >> 4) * 8]);
        }
    };

    for (int kk = 0; kk < KR; ++kk) {
        const int k = k0 + kk;
        __syncthreads();              // prev MFMA done reading Bs
        // ---- build B for this k from held gather regs ----
        if constexpr (L0S) {
            if (tid < 192) {
                float tv = tyt[nrow][kk * 3 + sub];
                f16x8 hv;
                hv[0] = (_Float16)(r0.x * tv); hv[1] = (_Float16)(r0.y * tv);
                hv[2] = (_Float16)(r1.x * tv); hv[3] = (_Float16)(r1.y * tv);
                hv[4] = (_Float16)(r2.x * tv); hv[5] = (_Float16)(r2.y * tv);
                hv[6] = (_Float16)0.f; hv[7] = (_Float16)0.f;
                *reinterpret_cast<f16x8*>(&Bs[nrow * SR + sub * 8]) = hv;
                if (sub == 0) {
                    f16x8 z = {};
                    *reinterpret_cast<f16x8*>(&Bs[nrow * SR + 24]) = z;
                }
            }
        } else {
            float tv0 = tyt[nrow][kk * 3 + 0];
            float tv1 = tyt[nrow][kk * 3 + 1];
            float tv2 = tyt[nrow][kk * 3 + 2];
#pragma unroll
            for (int o = 0; o < 3; ++o) {
                float tv = (o == 0) ? tv0 : (o == 1) ? tv1 : tv2;
#pragma unroll
                for (int qp = 0; qp < CQ / 2; ++qp) {
                    f16x8 hv;
                    hv[0] = (_Float16)(g[2 * qp].x * tv);
                    hv[1] = (_Float16)(g[2 * qp].y * tv);
                    hv[2] = (_Float16)(g[2 * qp].z * tv);
                    hv[3] = (_Float16)(g[2 * qp].w * tv);
                    hv[4] = (_Float16)(g[2 * qp + 1].x * tv);
                    hv[5] = (_Float16)(g[2 * qp + 1].y * tv);
                    hv[6] = (_Float16)(g[2 * qp + 1].z * tv);
                    hv[7] = (_Float16)(g[2 * qp + 1].w * tv);
                    *reinterpret_cast<f16x8*>(
                        &Bs[nrow * SR + o * CIN + sub * (CIN / TPR) + qp * 8]) = hv;
                }
            }
        }
        __syncthreads();              // B ready
        if (kk + 1 < KR) issue_gather(kk + 1);   // hide next gather under MFMA
        // ---- MFMA over CK3P with 2-stage A/B prefetch ----
        f16x8 aC[FM], bC[FN], aN[FM], bN[FN];
        loadA(k, 0, aC);
        loadB(0, bC);
#pragma unroll
        for (int kcb = 0; kcb < KCB; ++kcb) {
            if (kcb + 1 < KCB) { loadA(k, kcb + 1, aN); loadB(kcb + 1, bN); }
#pragma unroll
            for (int fm = 0; fm < FM; ++fm)
#pragma unroll
                for (int fn = 0; fn < FN; ++fn)
                    acc[fm][fn] = __builtin_amdgcn_mfma_f32_16x16x32_f16(
                        aC[fm], bC[fn], acc[fm][fn], 0, 0, 0);
            if (kcb + 1 < KCB) {
#pragma unroll
                for (int fm = 0; fm < FM; ++fm) aC[fm] = aN[fm];
#pragma unroll
                for (int fn = 0; fn < FN; ++fn) bC[fn] = bN[fn];
            }
        }
    }
    // ---- write raw partial (no bias/relu) ----
    float* dst = out + (size_t)ks * ((size_t)BB * NN * COUT);
#pragma unroll
    for (int fm = 0; fm < FM; ++fm) {
        const int ocb = oc0 + wm * FM * 16 + fm * 16 + ((lane >> 4) << 2);
#pragma unroll
        for (int fn = 0; fn < FN; ++fn) {
            int n = n0 + wn * FN * 16 + fn * 16 + (lane & 15);
            float4 o4;
            o4.x = acc[fm][fn][0]; o4.y = acc[fm][fn][1];
            o4.z = acc[fm][fn][2]; o4.w = acc[fm][fn][3];
            *reinterpret_cast<float4*>(&dst[(brow + n) * COUT + ocb]) = o4;
        }
    }
}

// ---------------------------------------------------------------------------
// Combine k-split partials: out = relu(sum_s p[s] + bias)
// ---------------------------------------------------------------------------
template <int COUT, int KS>
__global__ __launch_bounds__(256) void combine_kernel(const float* __restrict__ p,
                                                      const float* __restrict__ b2,
                                                      float* __restrict__ out) {
    constexpr size_t TOT = (size_t)BB * NN * COUT;
    size_t i = (size_t)blockIdx.x * 256 + threadIdx.x;
    if (i * 4 >= TOT) return;
    const float4* p4 = reinterpret_cast<const float4*>(p);
    float4 a = p4[i];
#pragma unroll
    for (int s = 1; s < KS; ++s) {
        float4 v = p4[i + s * (TOT / 4)];
        a.x += v.x; a.y += v.y; a.z += v.z; a.w += v.w;
    }
    float4 bb = *reinterpret_cast<const float4*>(&b2[(i * 4) % COUT]);
    float4 r;
    r.x = fmaxf(a.x + bb.x, 0.f); r.y = fmaxf(a.y + bb.y, 0.f);
    r.z = fmaxf(a.z + bb.z, 0.f); r.w = fmaxf(a.w + bb.w, 0.f);
    reinterpret_cast<float4*>(out)[i] = r;
}

// ---------------------------------------------------------------------------
// top-2 over N per (b, channel); L3 part fused from partials (p3, 2 splits).
// ---------------------------------------------------------------------------
__global__ __launch_bounds__(256) void top2_kernel(const float* __restrict__ f1,
                                                   const float* __restrict__ f2,
                                                   const float* __restrict__ f3,
                                                   const float* __restrict__ p3,
                                                   const float* __restrict__ b23,
                                                   float* __restrict__ out) {
    __shared__ float m1s[256], m2s[256];
    const int bid = blockIdx.x;
    const int b = bid / 480;
    const int ch = bid % 480;
    const size_t brow = (size_t)b * NN;
    float m1 = -INFINITY, m2 = -INFINITY;
    if (ch < 224) {
        const float* f; int C, c;
        if (ch < 32)       { f = f1; C = 32;  c = ch; }
        else if (ch < 96)  { f = f2; C = 64;  c = ch - 32; }
        else               { f = f3; C = 128; c = ch - 96; }
        for (int n = threadIdx.x; n < NN; n += 256) {
            float v = f[(brow + n) * C + c];
            if (v > m1) { m2 = m1; m1 = v; }
            else if (v > m2) m2 = v;
        }
    } else {
        const int c = ch - 224;
        const float bc = b23[c];
        constexpr size_t TOT3 = (size_t)BB * NN * 256;
        for (int n = threadIdx.x; n < NN; n += 256) {
            size_t o = (brow + n) * 256 + c;
            float v = fmaxf(p3[o] + p3[TOT3 + o] + bc, 0.f);
            if (v > m1) { m2 = m1; m1 = v; }
            else if (v > m2) m2 = v;
        }
    }
    m1s[threadIdx.x] = m1; m2s[threadIdx.x] = m2;
    __syncthreads();
    for (int s = 128; s > 0; s >>= 1) {
        if (threadIdx.x < s) {
            float a1 = m1s[threadIdx.x], a2 = m2s[threadIdx.x];
            float c1 = m1s[threadIdx.x + s], c2 = m2s[threadIdx.x + s];
            m1s[threadIdx.x] = fmaxf(a1, c1);
            m2s[threadIdx.x] = fmaxf(fminf(a1, c1), fmaxf(a2, c2));
        }
        __syncthreads();
    }
    if (threadIdx.x == 0) {
        out[(size_t)b * 960 + ch * 2 + 0] = m1s[0];
        out[(size_t)b * 960 + ch * 2 + 1] = m2s[0];
    }
}

extern "C" void kernel_launch(void* const* d_in, const int* in_sizes, int n_in,
                              void* d_out, int out_size, void* d_ws, size_t ws_size,
                              hipStream_t stream) {
    const float* pc = (const float*)d_in[0];
    const float *w1[4], *b1[4], *w2[4], *b2[4];
    for (int l = 0; l < 4; ++l) {
        w1[l] = (const float*)d_in[1 + 4 * l];
        b1[l] = (const float*)d_in[2 + 4 * l];
        w2[l] = (const float*)d_in[3 + 4 * l];
        b2[l] = (const float*)d_in[4 + 4 * l];
    }
    char* ws = (char*)d_ws;
    size_t off = 0;
    auto alloc = [&](size_t bytes) -> void* {
        void* p = ws + off;
        off = (off + bytes + 255) & ~(size_t)255;
        return p;
    };
    int* idxb     = (int*)alloc((size_t)BB * NN * KNN * 4);
    float* rel    = (float*)alloc((size_t)BB * NN * KNN * 3 * 4);
    float* ty0    = (float*)alloc((size_t)BB * NN * KNN * 3 * 4);
    float* ty1    = (float*)alloc((size_t)BB * NN * KNN * 3 * 4);
    float* ty2    = (float*)alloc((size_t)BB * NN * KNN * 3 * 4);
    float* ty3    = (float*)alloc((size_t)BB * NN * KNN * 3 * 4);
    _Float16* wfb = (_Float16*)alloc((size_t)KNN * 16 * 12 * 64 * 8 * 2);
    float* f1     = (float*)alloc((size_t)BB * NN * 32 * 4);
    float* f2     = (float*)alloc((size_t)BB * NN * 64 * 4);
    float* f3     = (float*)alloc((size_t)BB * NN * 128 * 4);
    float* pbuf   = (float*)alloc((size_t)4 * BB * NN * 128 * 4);  // 16.8 MB, reused

    knn_kernel<<<BB * NN / 4, 256, 0, stream>>>(pc, idxb, rel);

    taylor_all_kernel<<<(BB * NN * KNN + 255) / 256, 256, 0, stream>>>(
        rel, w1[0], b1[0], ty0, w1[1], b1[1], ty1, w1[2], b1[2], ty2, w1[3], b1[3], ty3);

    // ---- layer 0: cin=6 (CPAD=8), cout=32, CK3P=32, ksplit=4 ----
    {
        int total = KNN * 2 * 1 * 64 * 8;
        wsplit2_kernel<<<(total + 255) / 256, 256, 0, stream>>>(w2[0], wfb, 32, 6, 8, 2, 1, total);
    }
    convm_kernel<6, 32, 32, 64, 2, 2, 1, 2, 1, 4, true>
        <<<BB * 32 * 1 * 4, 256, 0, stream>>>(pc, idxb, ty0, wfb, pbuf);
    combine_kernel<32, 4><<<(BB * NN * 32 / 4 + 255) / 256, 256, 0, stream>>>(pbuf, b2[0], f1);

    // ---- layer 1: cin=32, cout=64, CK3P=96, ksplit=4 ----
    {
        int total = KNN * 4 * 3 * 64 * 8;
        wsplit2_kernel<<<(total + 255) / 256, 256, 0, stream>>>(w2[1], wfb, 64, 32, 32, 4, 3, total);
    }
    convm_kernel<32, 64, 96, 64, 4, 1, 1, 4, 1, 4, false>
        <<<BB * 32 * 1 * 4, 256, 0, stream>>>(f1, idxb, ty1, wfb, pbuf);
    combine_kernel<64, 4><<<(BB * NN * 64 / 4 + 255) / 256, 256, 0, stream>>>(pbuf, b2[1], f2);

    // ---- layer 2: cin=64, cout=128, CK3P=192, ksplit=4 ----
    {
        int total = KNN * 8 * 6 * 64 * 8;
        wsplit2_kernel<<<(total + 255) / 256, 256, 0, stream>>>(w2[2], wfb, 128, 64, 64, 8, 6, total);
    }
    convm_kernel<64, 128, 192, 64, 4, 1, 2, 4, 1, 4, false>
        <<<BB * 32 * 1 * 4, 256, 0, stream>>>(f2, idxb, ty2, wfb, pbuf);
    combine_kernel<128, 4><<<(BB * NN * 128 / 4 + 255) / 256, 256, 0, stream>>>(pbuf, b2[2], f3);

    // ---- layer 3: cin=128, cout=256, CK3P=384, oct=2, ksplit=2 ----
    {
        int total = KNN * 16 * 12 * 64 * 8;
        wsplit2_kernel<<<(total + 255) / 256, 256, 0, stream>>>(w2[3], wfb, 256, 128, 128, 16, 12, total);
    }
    convm_kernel<128, 256, 384, 64, 4, 1, 2, 4, 2, 2, false>
        <<<BB * 32 * 2 * 2, 256, 0, stream>>>(f3, idxb, ty3, wfb, pbuf);

    top2_kernel<<<BB * 480, 256, 0, stream>>>(f1, f2, f3, pbuf, b2[3], (float*)d_out);
}